// Round 3
// baseline (1399.802 us; speedup 1.0000x reference)
//
#include <hip/hip_runtime.h>
#include <hip/hip_bf16.h>

// Decoder: 6 layers of {SA, LN2d, CA, LN2d, FFN, LN2d}. fp32 I/O, bf16 MFMA.
// R7: (a) gemm_bt register blocking: per-wave 64x64 (MI4,NI4) for BM=256
//         modes (SA-QKV, CA-KV, FFN1) -> 2x FLOP per LDS byte; BM=128 with
//         per-wave 64x32 for N=512 modes (CA-Q, FFN2). 8 waves, BK=64,
//         double-buffered counted-vmcnt phase-split pipeline (R6 structure).
//         BM=256 spans 2 batches -> wave-uniform batch select for LN fixup.
//     (b) colsum_all: 8-way row split + atomicAdd (768 blocks, 64-deep
//         chains, 4 partial accumulators); zero_all zeroes cs + part.
//     (c) keeps XOR chunk-swizzle (bank-conflict=0) + bijective XCD swizzle.

typedef __bf16 bf16;
typedef bf16 bf16x8 __attribute__((ext_vector_type(8)));
typedef float f32x4 __attribute__((ext_vector_type(4)));

#define MFMA16(a, b, c) __builtin_amdgcn_mfma_f32_16x16x32_bf16(a, b, c, 0, 0, 0)

// async global->LDS, 16B/lane; LDS dest = wave-uniform base + lane*16
#define GLL16(gsrc, ldst)                                                          \
    __builtin_amdgcn_global_load_lds(                                              \
        (const __attribute__((address_space(1))) void*)(gsrc),                     \
        (__attribute__((address_space(3))) void*)(ldst), 16, 0, 0)

static constexpr int L_ = 6, C_ = 512, FF_ = 2048;
static constexpr int B_ = 64, T_ = 128;
static constexpr int M_ = B_ * T_;       // 8192
static constexpr float LNINV = 1.f / 65536.f;
static constexpr float EPS_ = 1e-5f;

// ---------------------------------------------------------------------------
// Zero colsum buffers (csA 9216, csQ 3072, csF 12288 floats) + part (2304).
__global__ __launch_bounds__(256) void zero_all(
    float* __restrict__ csA, float* __restrict__ csQ, float* __restrict__ csF,
    float* __restrict__ part)
{
    const int i = blockIdx.x * 256 + threadIdx.x;
    if (i < 6 * 1536) csA[i] = 0.f;
    if (i < 6 * 512)  csQ[i] = 0.f;
    if (i < 6 * 2048) csF[i] = 0.f;
    if (i < 18 * 64 * 2) part[i] = 0.f;
}

// x (fp32) -> y stream copy + bf16 operand
__global__ __launch_bounds__(256) void init_x(
    const float* __restrict__ xin, float* __restrict__ y, bf16* __restrict__ yb)
{
    const size_t i = ((size_t)blockIdx.x * 256 + threadIdx.x) * 8;
    float4 f0 = *(const float4*)(xin + i);
    float4 f1 = *(const float4*)(xin + i + 4);
    *(float4*)(y + i) = f0;
    *(float4*)(y + i + 4) = f1;
    bf16x8 v = {(bf16)f0.x, (bf16)f0.y, (bf16)f0.z, (bf16)f0.w,
                (bf16)f1.x, (bf16)f1.y, (bf16)f1.z, (bf16)f1.w};
    *(bf16x8*)(yb + i) = v;
}

__global__ __launch_bounds__(256) void to_bf16(
    const float* __restrict__ in, bf16* __restrict__ out)
{
    const size_t i = ((size_t)blockIdx.x * 256 + threadIdx.x) * 8;
    float4 f0 = *(const float4*)(in + i);
    float4 f1 = *(const float4*)(in + i + 4);
    bf16x8 v = {(bf16)f0.x, (bf16)f0.y, (bf16)f0.z, (bf16)f0.w,
                (bf16)f1.x, (bf16)f1.y, (bf16)f1.z, (bf16)f1.w};
    *(bf16x8*)(out + i) = v;
}

// ---------------------------------------------------------------------------
// Generic 64x64-tile fp32->bf16 transpose: src [R][C] -> dst [C][R]. grid z=1.
__global__ __launch_bounds__(256) void transpose_f32_bf16(
    const float* __restrict__ src, bf16* __restrict__ dst, int R, int C)
{
    __shared__ alignas(16) float t[64][68];
    const int r0 = blockIdx.y * 64, c0 = blockIdx.x * 64;
    const int tr = threadIdx.x >> 4;
    const int tc = (threadIdx.x & 15) * 4;
#pragma unroll
    for (int ro = 0; ro < 64; ro += 16)
        *(float4*)&t[tr + ro][tc] = *(const float4*)(src + (size_t)(r0 + tr + ro) * C + c0 + tc);
    __syncthreads();
    const int wc = (threadIdx.x & 7) * 8;
#pragma unroll
    for (int po = 0; po < 2; ++po) {
        const int oc = (threadIdx.x >> 3) + po * 32;
        bf16x8 v;
#pragma unroll
        for (int j = 0; j < 8; ++j) v[j] = (bf16)t[wc + j][oc];
        *(bf16x8*)(dst + (size_t)(c0 + oc) * R + r0 + wc) = v;
    }
}

// All per-head projection mats for all layers in one launch. z in [0,288):
// type=z/48 in {sa_wq,sa_wk,sa_wv,ca_wq,ca_wk,ca_wv}, l=(z%48)/8, h=z%8.
__global__ __launch_bounds__(256) void head_repack(
    const float* __restrict__ sa_wq, const float* __restrict__ sa_wk,
    const float* __restrict__ sa_wv, const float* __restrict__ ca_wq,
    const float* __restrict__ ca_wk, const float* __restrict__ ca_wv,
    bf16* __restrict__ Wsa, bf16* __restrict__ Wcaq, bf16* __restrict__ Wcakv)
{
    __shared__ alignas(16) float t[64][68];
    const int z = blockIdx.z;
    const int type = z / 48, rem = z % 48, l = rem >> 3, h = rem & 7;
    const float* srcs[6] = {sa_wq, sa_wk, sa_wv, ca_wq, ca_wk, ca_wv};
    const float* s = srcs[type] + (size_t)(l * 8 + h) * 512 * 64;
    bf16* d;
    if (type < 3)       d = Wsa   + ((size_t)l * 1536 + type * 512 + h * 64) * 512;
    else if (type == 3) d = Wcaq  + ((size_t)l * 512 + h * 64) * 512;
    else                d = Wcakv + ((size_t)l * 1024 + (type - 4) * 512 + h * 64) * 512;
    const int r0 = blockIdx.y * 64;  // over R=512; C=64 single tile
    const int tr = threadIdx.x >> 4;
    const int tc = (threadIdx.x & 15) * 4;
#pragma unroll
    for (int ro = 0; ro < 64; ro += 16)
        *(float4*)&t[tr + ro][tc] = *(const float4*)(s + (size_t)(r0 + tr + ro) * 64 + tc);
    __syncthreads();
    const int wc = (threadIdx.x & 7) * 8;
#pragma unroll
    for (int po = 0; po < 2; ++po) {
        const int oc = (threadIdx.x >> 3) + po * 32;  // original col (d)
        bf16x8 v;
#pragma unroll
        for (int j = 0; j < 8; ++j) v[j] = (bf16)t[wc + j][oc];
        *(bf16x8*)(d + (size_t)oc * 512 + r0 + wc) = v;
    }
}

// Column sums of the fixup-needing weights, from the ORIGINAL fp32 layouts.
// 8-way row split (blockIdx.y): each thread sums 64 rows, atomicAdd into cs.
__global__ __launch_bounds__(256) void colsum_all(
    const float* __restrict__ sa_wq, const float* __restrict__ sa_wk,
    const float* __restrict__ sa_wv, const float* __restrict__ ca_wq,
    const float* __restrict__ ff_w1,
    float* __restrict__ csA, float* __restrict__ csQ, float* __restrict__ csF)
{
    const int t = blockIdx.x * 256 + threadIdx.x;
    const int l = t >> 12, u = t & 4095;
    const int r0 = blockIdx.y * 64;
    const float* base;
    int stride;
    float* out;
    if (u < 1536) {
        const int p = u >> 9, h = (u >> 6) & 7, d = u & 63;
        const float* w = (p == 0) ? sa_wq : (p == 1) ? sa_wk : sa_wv;
        base = w + (size_t)(l * 8 + h) * 512 * 64 + d;
        stride = 64;
        out = &csA[l * 1536 + u];
    } else if (u < 2048) {
        const int v = u - 1536, h = v >> 6, d = v & 63;
        base = ca_wq + (size_t)(l * 8 + h) * 512 * 64 + d;
        stride = 64;
        out = &csQ[l * 512 + v];
    } else {
        const int f = u - 2048;
        base = ff_w1 + (size_t)l * 512 * 2048 + f;
        stride = 2048;
        out = &csF[l * 2048 + f];
    }
    const float* p = base + (size_t)r0 * stride;
    float s0 = 0.f, s1 = 0.f, s2 = 0.f, s3 = 0.f;
#pragma unroll 4
    for (int c = 0; c < 64; c += 4) {
        s0 += p[0];
        s1 += p[(size_t)stride];
        s2 += p[(size_t)2 * stride];
        s3 += p[(size_t)3 * stride];
        p += (size_t)4 * stride;
    }
    atomicAdd(out, (s0 + s1) + (s2 + s3));
}

// ---------------------------------------------------------------------------
// GEMM out[M][N] = A[M][K] * BT[N][K]^T. BK=64, double-buffered, 2-deep
// counted-vmcnt pipeline, phase-split (2 MFMA clusters/tile with setprio),
// XOR-swizzled LDS, XCD block swizzle. 8 waves (512 thr). BN=128.
// BM256: waves 4x2, per-wave 64x64 (MI4,NI4)  [SA-QKV, CA-KV, FFN1]
// BM128: waves 2x4, per-wave 64x32 (MI4,NI2)  [CA-Q, FFN2]
// LN fixup (slotPrev>=0): val*rstd + bias - mu*rstd*cs[n]; batch selected
// per wave via (m0+wr)>>7 (BM256 spans 2 batches).
// MODE 0: SA QKV (N=1536, fixup) -> qb/kb/vTb
// MODE 1: CA Q   (N=512, fixup)  -> qb
// MODE 2: CA KV  (N=1024, plain bias) -> kb/vTb
// MODE 3: FFN1   (fixup + relu) -> hbuf bf16
// MODE 4: FFN2   (plain bias + residual-normfix add into y, fused stats)
template <int MODE, int BM>
__global__ __launch_bounds__(512) void gemm_bt(
    const bf16* __restrict__ A, const bf16* __restrict__ BT,
    const float* __restrict__ b0, const float* __restrict__ b1,
    const float* __restrict__ b2, const float* __restrict__ cs,
    float2* __restrict__ part, int slotPrev, int slotNew,
    bf16* __restrict__ o0, bf16* __restrict__ o1, bf16* __restrict__ o2,
    float* __restrict__ y, bf16* __restrict__ ybf, int N, int K)
{
    constexpr int WC = (BM == 256) ? 2 : 4;   // col-waves (row-waves = 8/WC)
    constexpr int MI = 4;
    constexpr int NI = (BM == 256) ? 4 : 2;
    constexpr int AR = BM / 8;           // A rows per wave (staging)
    constexpr int AGLL = BM / 64;        // A GLLs per wave per K-tile
    constexpr int VG = AGLL + 2;         // total GLLs per wave per K-tile
    __shared__ alignas(16) bf16 as[2][BM][64];
    __shared__ alignas(16) bf16 bs[2][128][64];
    const int tid = threadIdx.x, wave = tid >> 6, lane = tid & 63;

    // bijective XCD-aware swizzle of the flat (x-fastest) workgroup id
    const int gx = gridDim.x;
    int wgid = blockIdx.y * gx + blockIdx.x;
    {
        const int nwg = gx * gridDim.y;
        const int q = nwg >> 3, r = nwg & 7;
        const int xcd = wgid & 7, idx = wgid >> 3;
        wgid = (xcd < r ? xcd * (q + 1) : r * (q + 1) + (xcd - r) * q) + idx;
    }
    const int m0 = (wgid / gx) * BM, n0 = (wgid % gx) * 128;

    const int wr = ((WC == 2) ? (wave >> 1) : (wave >> 2)) * 64;
    const int wc = (wave & (WC - 1)) * (128 / WC);
    const int fr = lane & 15, fq = lane >> 4;
    const int xr = fr & 7;

    float mu = 0.f, rstd = 1.f;
    if (slotPrev >= 0) {
        float2 p = part[slotPrev * 64 + ((m0 + wr) >> 7)];
        mu = p.x * LNINV;
        rstd = rsqrtf(p.y * LNINV - mu * mu + EPS_);
    }

    // staging geometry: one GLL16 covers 8 rows x 128B (8 lanes/row, 16B/lane).
    // LDS dest linear; the GLOBAL source column is pre-swizzled so physical
    // chunk p of row r holds logical chunk p ^ (r&7).
    const int rlane = lane >> 3;                    // row within an 8-row group
    const int scol = ((lane & 7) ^ rlane) * 8;      // swizzled col (bf16 elems)
    const bf16* pa = A + (size_t)(m0 + wave * AR + rlane) * K + scol;
    const bf16* pb = BT + (size_t)(n0 + wave * 16 + rlane) * K + scol;

    auto stage = [&](int buf, int k0) {
#pragma unroll
        for (int i = 0; i < AGLL; ++i)
            GLL16(pa + k0 + (size_t)(8 * i) * K, &as[buf][wave * AR + 8 * i][0]);
#pragma unroll
        for (int i = 0; i < 2; ++i)
            GLL16(pb + k0 + (size_t)(8 * i) * K, &bs[buf][wave * 16 + 8 * i][0]);
    };

    f32x4 acc[MI][NI] = {};
    bf16x8 af[MI], bfv[NI];
    auto frags = [&](int buf, int kk) {
#pragma unroll
        for (int mi = 0; mi < MI; ++mi)
            af[mi] = *(const bf16x8*)&as[buf][wr + mi * 16 + fr][(((kk << 2) + fq) ^ xr) << 3];
#pragma unroll
        for (int ni = 0; ni < NI; ++ni)
            bfv[ni] = *(const bf16x8*)&bs[buf][wc + ni * 16 + fr][(((kk << 2) + fq) ^ xr) << 3];
    };
    auto cluster = [&]() {
        __builtin_amdgcn_s_setprio(1);
#pragma unroll
        for (int mi = 0; mi < MI; ++mi)
#pragma unroll
            for (int ni = 0; ni < NI; ++ni)
                acc[mi][ni] = MFMA16(af[mi], bfv[ni], acc[mi][ni]);
        __builtin_amdgcn_s_setprio(0);
    };

    const int nt = K >> 6;           // K-tiles of 64
    stage(0, 0);
    stage(1, 64);

    int cur = 0;
    for (int t = 0; t < nt - 1; ++t) {
        // tile t's loads landed (tile t+1 stays in flight); make visible.
        asm volatile("s_waitcnt vmcnt(%0)\n\ts_barrier" :: "n"(VG) : "memory");
        // phase 0 (kk=0)
        frags(cur, 0);
        asm volatile("s_waitcnt lgkmcnt(0)" ::: "memory");
        __builtin_amdgcn_sched_barrier(0);
        cluster();
        // phase 1 (kk=1)
        frags(cur, 1);
        asm volatile("s_waitcnt lgkmcnt(0)" ::: "memory");
        __builtin_amdgcn_sched_barrier(0);
        __builtin_amdgcn_s_barrier();              // all waves done reading buf
        if (t + 2 < nt) stage(cur, (t + 2) << 6);  // refill under MFMA below
        cluster();
        cur ^= 1;
    }
    asm volatile("s_waitcnt vmcnt(0)\n\ts_barrier" ::: "memory");
    frags(cur, 0);
    asm volatile("s_waitcnt lgkmcnt(0)" ::: "memory");
    __builtin_amdgcn_sched_barrier(0);
    cluster();
    frags(cur, 1);
    asm volatile("s_waitcnt lgkmcnt(0)" ::: "memory");
    __builtin_amdgcn_sched_barrier(0);
    cluster();

    float s = 0.f, ss = 0.f;
    const float murs = mu * rstd;
#pragma unroll
    for (int mi = 0; mi < MI; ++mi) {
#pragma unroll
        for (int ni = 0; ni < NI; ++ni) {
            const int n = n0 + wc + ni * 16 + fr;
#pragma unroll
            for (int reg = 0; reg < 4; ++reg) {
                const int r = m0 + wr + mi * 16 + fq * 4 + reg;
                float val = acc[mi][ni][reg];
                if constexpr (MODE == 0) {
                    const int p = n >> 9, hd = n & 511, d = n & 63, hh = (n >> 6) & 7;
                    const int bb = r >> 7, tt = r & 127;
                    const float* bias = (p == 0) ? b0 : (p == 1 ? b1 : b2);
                    val = val * rstd + bias[hd] - murs * cs[n];
                    const size_t bh = (size_t)(bb * 8 + hh);
                    if (p == 0)      o0[(bh * 128 + tt) * 64 + d] = (bf16)val;
                    else if (p == 1) o1[(bh * 128 + tt) * 64 + d] = (bf16)val;
                    else             o2[(bh * 64 + d) * 128 + tt] = (bf16)val;
                } else if constexpr (MODE == 1) {
                    const int d = n & 63, hh = (n >> 6) & 7;
                    const int bb = r >> 7, tt = r & 127;
                    val = val * rstd + b0[n] - murs * cs[n];
                    o0[((size_t)(bb * 8 + hh) * 128 + tt) * 64 + d] = (bf16)val;
                } else if constexpr (MODE == 2) {
                    const int p = n >> 9, hd = n & 511, d = n & 63, hh = (n >> 6) & 7;
                    const int bb = r >> 7, tt = r & 127;
                    val += (p == 0) ? b1[hd] : b2[hd];
                    const size_t bh = (size_t)(bb * 8 + hh);
                    if (p == 0) o1[(bh * 128 + tt) * 64 + d] = (bf16)val;
                    else        o2[(bh * 64 + d) * 128 + tt] = (bf16)val;
                } else if constexpr (MODE == 3) {
                    val = val * rstd + b0[n] - murs * cs[n];
                    val = fmaxf(val, 0.f);
                    o0[(size_t)r * 2048 + n] = (bf16)val;
                } else {  // MODE 4: residual-normfix add + fused stats
                    const size_t idx = (size_t)r * 512 + n;
                    const float v = (y[idx] - mu) * rstd + val + b0[n];
                    y[idx] = v;
                    ybf[idx] = (bf16)v;
                    s += v;
                    ss += v * v;
                }
            }
        }
    }
    if constexpr (MODE == 4) {
        for (int off = 32; off; off >>= 1) { s += __shfl_xor(s, off); ss += __shfl_xor(ss, off); }
        __shared__ float rs[8], rss[8];
        if (lane == 0) { rs[wave] = s; rss[wave] = ss; }
        __syncthreads();
        if (tid == 0) {
            float sa = 0.f, sb = 0.f;
#pragma unroll
            for (int w = 0; w < 8; ++w) { sa += rs[w]; sb += rss[w]; }
            float2* dst = &part[slotNew * 64 + (m0 >> 7)];
            atomicAdd(&dst->x, sa);
            atomicAdd(&dst->y, sb);
        }
    }
}

// ---------------------------------------------------------------------------
// Attention for one (b,h). exp fused into QK epilogue (in-register), row-sums
// via shfl reduce + 2-way LDS partials (no max: |S|~O(1), shift-invariant).
// Epilogue: y += normfix(residual) + P V / rowsum, fused stats -> part.
__global__ __launch_bounds__(256) void attn_kernel(
    const bf16* __restrict__ q, const bf16* __restrict__ k,
    const bf16* __restrict__ vT, float* __restrict__ y, bf16* __restrict__ ybf,
    float2* __restrict__ part, int slotPrev, int slotNew)
{
    __shared__ alignas(16) bf16 sP[128][136];
    __shared__ float sPart[2][128];
    const int bh = blockIdx.x;
    const int bb = bh >> 3, hh = bh & 7;
    const bf16* Q = q + (size_t)bh * 128 * 64;
    const bf16* Kp = k + (size_t)bh * 128 * 64;
    const bf16* V = vT + (size_t)bh * 64 * 128;
    const int tid = threadIdx.x, wave = tid >> 6, lane = tid & 63;
    const int wr = (wave >> 1) * 64, wc = (wave & 1) * 64;
    const int fr = lane & 15, fq = lane >> 4;

    float mu = 0.f, rstd = 1.f;
    if (slotPrev >= 0) {
        float2 p = part[slotPrev * 64 + bb];
        mu = p.x * LNINV;
        rstd = rsqrtf(p.y * LNINV - mu * mu + EPS_);
    }

    // S = Q K^T (128x128, K=64)
    f32x4 acc[4][4] = {};
#pragma unroll
    for (int k0 = 0; k0 < 64; k0 += 32) {
        bf16x8 af[4], bfv[4];
#pragma unroll
        for (int mi = 0; mi < 4; ++mi)
            af[mi] = *(const bf16x8*)(Q + (size_t)(wr + mi * 16 + fr) * 64 + k0 + fq * 8);
#pragma unroll
        for (int ni = 0; ni < 4; ++ni)
            bfv[ni] = *(const bf16x8*)(Kp + (size_t)(wc + ni * 16 + fr) * 64 + k0 + fq * 8);
#pragma unroll
        for (int mi = 0; mi < 4; ++mi)
#pragma unroll
            for (int ni = 0; ni < 4; ++ni)
                acc[mi][ni] = MFMA16(af[mi], bfv[ni], acc[mi][ni]);
    }

    // P = exp(S/8) in registers; store P + per-(wavecol,row) partial sums
    const int colw = wave & 1;
#pragma unroll
    for (int mi = 0; mi < 4; ++mi) {
#pragma unroll
        for (int reg = 0; reg < 4; ++reg) {
            const int r = wr + mi * 16 + fq * 4 + reg;
            float rsum = 0.f;
#pragma unroll
            for (int ni = 0; ni < 4; ++ni) {
                const float e = __expf(acc[mi][ni][reg] * 0.125f);
                sP[r][wc + ni * 16 + fr] = (bf16)e;
                rsum += e;
            }
            rsum += __shfl_xor(rsum, 1);
            rsum += __shfl_xor(rsum, 2);
            rsum += __shfl_xor(rsum, 4);
            rsum += __shfl_xor(rsum, 8);
            if (fr == 0) sPart[colw][r] = rsum;
        }
    }
    __syncthreads();

    // O = P V (128x64, K=128)
    f32x4 acc2[2][4] = {};
#pragma unroll
    for (int k0 = 0; k0 < 128; k0 += 32) {
        bf16x8 af[2], bfv[4];
#pragma unroll
        for (int mi = 0; mi < 2; ++mi)
            af[mi] = *(const bf16x8*)&sP[wave * 32 + mi * 16 + fr][k0 + fq * 8];
#pragma unroll
        for (int ni = 0; ni < 4; ++ni)
            bfv[ni] = *(const bf16x8*)(V + (size_t)(ni * 16 + fr) * 128 + k0 + fq * 8);
#pragma unroll
        for (int mi = 0; mi < 2; ++mi)
#pragma unroll
            for (int ni = 0; ni < 4; ++ni)
                acc2[mi][ni] = MFMA16(af[mi], bfv[ni], acc2[mi][ni]);
    }

    float inv[2][4];
#pragma unroll
    for (int mi = 0; mi < 2; ++mi)
#pragma unroll
        for (int reg = 0; reg < 4; ++reg) {
            const int r = wave * 32 + mi * 16 + fq * 4 + reg;
            inv[mi][reg] = 1.f / (sPart[0][r] + sPart[1][r]);
        }

    float s = 0.f, ss = 0.f;
#pragma unroll
    for (int mi = 0; mi < 2; ++mi)
#pragma unroll
        for (int ni = 0; ni < 4; ++ni)
#pragma unroll
            for (int reg = 0; reg < 4; ++reg) {
                const int r = wave * 32 + mi * 16 + fq * 4 + reg;
                const int d = ni * 16 + fr;
                const size_t idx = ((size_t)(bb * 128 + r)) * 512 + hh * 64 + d;
                const float v = (y[idx] - mu) * rstd + acc2[mi][ni][reg] * inv[mi][reg];
                y[idx] = v;
                ybf[idx] = (bf16)v;
                s += v;
                ss += v * v;
            }
    for (int off = 32; off; off >>= 1) { s += __shfl_xor(s, off); ss += __shfl_xor(ss, off); }
    __shared__ float rs[4], rss[4];
    if (lane == 0) { rs[wave] = s; rss[wave] = ss; }
    __syncthreads();
    if (tid == 0) {
        float2* dst = &part[slotNew * 64 + bb];
        atomicAdd(&dst->x, rs[0] + rs[1] + rs[2] + rs[3]);
        atomicAdd(&dst->y, rss[0] + rss[1] + rss[2] + rss[3]);
    }
}

// ---------------------------------------------------------------------------
// d_out = (y - mu) * rstd, fp32. grid 4096 x 256, 4 elems/thread.
__global__ __launch_bounds__(256) void final_norm(
    const float* __restrict__ y, const float2* __restrict__ part, int slot,
    float* __restrict__ out)
{
    const size_t i = ((size_t)blockIdx.x * 256 + threadIdx.x) * 4;
    const int b = (int)(i >> 16);
    float2 p = part[slot * 64 + b];
    const float mu = p.x * LNINV;
    const float rstd = rsqrtf(p.y * LNINV - mu * mu + EPS_);
    float4 v = *(const float4*)(y + i);
    float4 o = {(v.x - mu) * rstd, (v.y - mu) * rstd, (v.z - mu) * rstd, (v.w - mu) * rstd};
    *(float4*)(out + i) = o;
}

// ---------------------------------------------------------------------------
extern "C" void kernel_launch(void* const* d_in, const int* in_sizes, int n_in,
                              void* d_out, int out_size, void* d_ws, size_t ws_size,
                              hipStream_t stream)
{
    (void)in_sizes; (void)n_in; (void)out_size; (void)ws_size;
    const float* x_in  = (const float*)d_in[0];
    const float* enc   = (const float*)d_in[1];
    const float* sa_wq = (const float*)d_in[2];
    const float* sa_bq = (const float*)d_in[3];
    const float* sa_wk = (const float*)d_in[4];
    const float* sa_bk = (const float*)d_in[5];
    const float* sa_wv = (const float*)d_in[6];
    const float* sa_bv = (const float*)d_in[7];
    const float* ca_wq = (const float*)d_in[8];
    const float* ca_bq = (const float*)d_in[9];
    const float* ca_wk = (const float*)d_in[10];
    const float* ca_bk = (const float*)d_in[11];
    const float* ca_wv = (const float*)d_in[12];
    const float* ca_bv = (const float*)d_in[13];
    const float* ff_w1 = (const float*)d_in[14];
    const float* ff_b1 = (const float*)d_in[15];
    const float* ff_w2 = (const float*)d_in[16];
    const float* ff_b2 = (const float*)d_in[17];

    char* wsp = (char*)d_ws;
    auto alloc = [&](size_t bytes) -> char* {
        char* p = wsp;
        wsp += (bytes + 255) & ~(size_t)255;
        return p;
    };
    float* y     = (float*)alloc((size_t)M_ * 512 * 4);           // unnormalized stream
    bf16*  ybf   = (bf16*)alloc((size_t)M_ * 512 * 2);            // bf16 GEMM operand
    bf16*  encbf = (bf16*)alloc((size_t)M_ * 512 * 2);
    char*  shreg = alloc((size_t)M_ * 2048 * 2);                  // qkv bufs / FFN hidden
    bf16*  WsaA  = (bf16*)alloc((size_t)L_ * 1536 * 512 * 2);     // repacked, all layers
    bf16*  WcaqA = (bf16*)alloc((size_t)L_ * 512 * 512 * 2);
    bf16*  WcakvA= (bf16*)alloc((size_t)L_ * 1024 * 512 * 2);
    bf16*  Wff1  = (bf16*)alloc((size_t)2048 * 512 * 2);          // per-layer
    bf16*  Wff2  = (bf16*)alloc((size_t)512 * 2048 * 2);
    float* csA   = (float*)alloc((size_t)L_ * 1536 * 4);          // colsums
    float* csQ   = (float*)alloc((size_t)L_ * 512 * 4);
    float* csF   = (float*)alloc((size_t)L_ * 2048 * 4);
    float2* part = (float2*)alloc(18 * 64 * sizeof(float2));

    bf16* qb   = (bf16*)shreg;
    bf16* kb   = (bf16*)(shreg + (size_t)512 * 128 * 64 * 2);
    bf16* vTb  = (bf16*)(shreg + (size_t)2 * 512 * 128 * 64 * 2);
    bf16* hbuf = (bf16*)shreg;  // overlaps qkv (disjoint lifetime)

    dim3 tb(256), tbg(512);
    zero_all<<<48, tb, 0, stream>>>(csA, csQ, csF, (float*)part);
    init_x<<<2048, tb, 0, stream>>>(x_in, y, ybf);
    to_bf16<<<2048, tb, 0, stream>>>(enc, encbf);
    head_repack<<<dim3(1, 8, 288), tb, 0, stream>>>(sa_wq, sa_wk, sa_wv, ca_wq, ca_wk, ca_wv,
                                                    WsaA, WcaqA, WcakvA);
    colsum_all<<<dim3(96, 8), tb, 0, stream>>>(sa_wq, sa_wk, sa_wv, ca_wq, ff_w1, csA, csQ, csF);

    for (int l = 0; l < L_; ++l) {
        transpose_f32_bf16<<<dim3(32, 8, 1), tb, 0, stream>>>(ff_w1 + (size_t)l * 512 * 2048, Wff1, 512, 2048);
        transpose_f32_bf16<<<dim3(8, 32, 1), tb, 0, stream>>>(ff_w2 + (size_t)l * 2048 * 512, Wff2, 2048, 512);
        const int sPrev = (l == 0) ? -1 : (l - 1) * 3 + 2;
        // ---- self attention
        gemm_bt<0, 256><<<dim3(12, 32), tbg, 0, stream>>>(ybf, WsaA + (size_t)l * 1536 * 512,
            sa_bq + l * 512, sa_bk + l * 512, sa_bv + l * 512, csA + l * 1536,
            part, sPrev, -1, qb, kb, vTb, nullptr, nullptr, 1536, 512);
        attn_kernel<<<512, tb, 0, stream>>>(qb, kb, vTb, y, ybf, part, sPrev, l * 3 + 0);
        // ---- cross attention
        gemm_bt<1, 128><<<dim3(4, 64), tbg, 0, stream>>>(ybf, WcaqA + (size_t)l * 512 * 512,
            ca_bq + l * 512, nullptr, nullptr, csQ + l * 512,
            part, l * 3 + 0, -1, qb, nullptr, nullptr, nullptr, nullptr, 512, 512);
        gemm_bt<2, 256><<<dim3(8, 32), tbg, 0, stream>>>(encbf, WcakvA + (size_t)l * 1024 * 512,
            nullptr, ca_bk + l * 512, ca_bv + l * 512, nullptr,
            part, -1, -1, nullptr, kb, vTb, nullptr, nullptr, 1024, 512);
        attn_kernel<<<512, tb, 0, stream>>>(qb, kb, vTb, y, ybf, part, l * 3 + 0, l * 3 + 1);
        // ---- feed-forward
        gemm_bt<3, 256><<<dim3(16, 32), tbg, 0, stream>>>(ybf, Wff1,
            ff_b1 + l * 2048, nullptr, nullptr, csF + l * 2048,
            part, l * 3 + 1, -1, hbuf, nullptr, nullptr, nullptr, nullptr, 2048, 512);
        gemm_bt<4, 128><<<dim3(4, 64), tbg, 0, stream>>>(hbuf, Wff2,
            ff_b2 + l * 512, nullptr, nullptr, nullptr,
            part, l * 3 + 1, l * 3 + 2, nullptr, nullptr, nullptr, y, ybf, 512, 2048);
    }
    final_norm<<<4096, tb, 0, stream>>>(y, part, 17, (float*)d_out);
}

// Round 4
// 1320.410 us; speedup vs baseline: 1.0601x; 1.0601x over previous
//
#include <hip/hip_runtime.h>
#include <hip/hip_bf16.h>

// Decoder: 6 layers of {SA, LN2d, CA, LN2d, FFN, LN2d}. fp32 I/O, bf16 MFMA.
// R8: gemm_bt -> m97 geometry + counted-vmcnt dbuf:
//   4-wave blocks (2x2 waves of 64x64, MI4NI4), BM=128, BN=128/64, BK=32,
//   double-buffered LDS (32KB) -> 4 blocks/CU (__launch_bounds__(256,4)).
//   Independent blocks provide the MFMA<->mem overlap (m114); barriers are
//   intra-block. Counted vmcnt(VG) at tile top (never 0 in-loop); second
//   barrier waits lgkmcnt(0) only. No setprio/sched_barrier (compiler's
//   fine-grained lgkmcnt interleave is better). chunk-XOR swizzle at BK=32:
//   phys chunk = logical ^ (row&3). FFN transposes hoisted to one z=12
//   launch before the layer loop. LN folded into GEMM epilogues (unchanged).

typedef __bf16 bf16;
typedef bf16 bf16x8 __attribute__((ext_vector_type(8)));
typedef float f32x4 __attribute__((ext_vector_type(4)));

#define MFMA16(a, b, c) __builtin_amdgcn_mfma_f32_16x16x32_bf16(a, b, c, 0, 0, 0)

// async global->LDS, 16B/lane; LDS dest = wave-uniform base + lane*16
#define GLL16(gsrc, ldst)                                                          \
    __builtin_amdgcn_global_load_lds(                                              \
        (const __attribute__((address_space(1))) void*)(gsrc),                     \
        (__attribute__((address_space(3))) void*)(ldst), 16, 0, 0)

static constexpr int L_ = 6, C_ = 512, FF_ = 2048;
static constexpr int B_ = 64, T_ = 128;
static constexpr int M_ = B_ * T_;       // 8192
static constexpr float LNINV = 1.f / 65536.f;
static constexpr float EPS_ = 1e-5f;

// ---------------------------------------------------------------------------
// Zero colsum buffers + part.
__global__ __launch_bounds__(256) void zero_all(
    float* __restrict__ csA, float* __restrict__ csQ, float* __restrict__ csF,
    float* __restrict__ part)
{
    const int i = blockIdx.x * 256 + threadIdx.x;
    if (i < 6 * 1536) csA[i] = 0.f;
    if (i < 6 * 512)  csQ[i] = 0.f;
    if (i < 6 * 2048) csF[i] = 0.f;
    if (i < 18 * 64 * 2) part[i] = 0.f;
}

// x (fp32) -> y stream copy + bf16 operand
__global__ __launch_bounds__(256) void init_x(
    const float* __restrict__ xin, float* __restrict__ y, bf16* __restrict__ yb)
{
    const size_t i = ((size_t)blockIdx.x * 256 + threadIdx.x) * 8;
    float4 f0 = *(const float4*)(xin + i);
    float4 f1 = *(const float4*)(xin + i + 4);
    *(float4*)(y + i) = f0;
    *(float4*)(y + i + 4) = f1;
    bf16x8 v = {(bf16)f0.x, (bf16)f0.y, (bf16)f0.z, (bf16)f0.w,
                (bf16)f1.x, (bf16)f1.y, (bf16)f1.z, (bf16)f1.w};
    *(bf16x8*)(yb + i) = v;
}

__global__ __launch_bounds__(256) void to_bf16(
    const float* __restrict__ in, bf16* __restrict__ out)
{
    const size_t i = ((size_t)blockIdx.x * 256 + threadIdx.x) * 8;
    float4 f0 = *(const float4*)(in + i);
    float4 f1 = *(const float4*)(in + i + 4);
    bf16x8 v = {(bf16)f0.x, (bf16)f0.y, (bf16)f0.z, (bf16)f0.w,
                (bf16)f1.x, (bf16)f1.y, (bf16)f1.z, (bf16)f1.w};
    *(bf16x8*)(out + i) = v;
}

// ---------------------------------------------------------------------------
// FFN weight repack for ALL layers, one launch. grid (32, 8, 12):
// z<6: ff_w1 layer z [512][2048] -> W1 [2048][512] bf16
// z>=6: ff_w2 layer z-6 [2048][512] -> W2 [512][2048] bf16
__global__ __launch_bounds__(256) void ff_repack(
    const float* __restrict__ ff_w1, const float* __restrict__ ff_w2,
    bf16* __restrict__ W1, bf16* __restrict__ W2)
{
    __shared__ alignas(16) float t[64][68];
    const int z = blockIdx.z;
    const float* src;
    bf16* dst;
    int R, C, r0, c0;
    if (z < 6) {
        src = ff_w1 + (size_t)z * 512 * 2048;
        dst = W1 + (size_t)z * 2048 * 512;
        R = 512; C = 2048;
        r0 = blockIdx.y * 64;
        c0 = blockIdx.x * 64;
    } else {
        src = ff_w2 + (size_t)(z - 6) * 2048 * 512;
        dst = W2 + (size_t)(z - 6) * 512 * 2048;
        R = 2048; C = 512;
        r0 = (blockIdx.y * 4 + (blockIdx.x >> 3)) * 64;
        c0 = (blockIdx.x & 7) * 64;
    }
    const int tr = threadIdx.x >> 4;
    const int tc = (threadIdx.x & 15) * 4;
#pragma unroll
    for (int ro = 0; ro < 64; ro += 16)
        *(float4*)&t[tr + ro][tc] = *(const float4*)(src + (size_t)(r0 + tr + ro) * C + c0 + tc);
    __syncthreads();
    const int wc = (threadIdx.x & 7) * 8;
#pragma unroll
    for (int po = 0; po < 2; ++po) {
        const int oc = (threadIdx.x >> 3) + po * 32;
        bf16x8 v;
#pragma unroll
        for (int j = 0; j < 8; ++j) v[j] = (bf16)t[wc + j][oc];
        *(bf16x8*)(dst + (size_t)(c0 + oc) * R + r0 + wc) = v;
    }
}

// All per-head projection mats for all layers in one launch. z in [0,288):
// type=z/48 in {sa_wq,sa_wk,sa_wv,ca_wq,ca_wk,ca_wv}, l=(z%48)/8, h=z%8.
__global__ __launch_bounds__(256) void head_repack(
    const float* __restrict__ sa_wq, const float* __restrict__ sa_wk,
    const float* __restrict__ sa_wv, const float* __restrict__ ca_wq,
    const float* __restrict__ ca_wk, const float* __restrict__ ca_wv,
    bf16* __restrict__ Wsa, bf16* __restrict__ Wcaq, bf16* __restrict__ Wcakv)
{
    __shared__ alignas(16) float t[64][68];
    const int z = blockIdx.z;
    const int type = z / 48, rem = z % 48, l = rem >> 3, h = rem & 7;
    const float* srcs[6] = {sa_wq, sa_wk, sa_wv, ca_wq, ca_wk, ca_wv};
    const float* s = srcs[type] + (size_t)(l * 8 + h) * 512 * 64;
    bf16* d;
    if (type < 3)       d = Wsa   + ((size_t)l * 1536 + type * 512 + h * 64) * 512;
    else if (type == 3) d = Wcaq  + ((size_t)l * 512 + h * 64) * 512;
    else                d = Wcakv + ((size_t)l * 1024 + (type - 4) * 512 + h * 64) * 512;
    const int r0 = blockIdx.y * 64;  // over R=512; C=64 single tile
    const int tr = threadIdx.x >> 4;
    const int tc = (threadIdx.x & 15) * 4;
#pragma unroll
    for (int ro = 0; ro < 64; ro += 16)
        *(float4*)&t[tr + ro][tc] = *(const float4*)(s + (size_t)(r0 + tr + ro) * 64 + tc);
    __syncthreads();
    const int wc = (threadIdx.x & 7) * 8;
#pragma unroll
    for (int po = 0; po < 2; ++po) {
        const int oc = (threadIdx.x >> 3) + po * 32;  // original col (d)
        bf16x8 v;
#pragma unroll
        for (int j = 0; j < 8; ++j) v[j] = (bf16)t[wc + j][oc];
        *(bf16x8*)(d + (size_t)oc * 512 + r0 + wc) = v;
    }
}

// Column sums of the fixup-needing weights, from the ORIGINAL fp32 layouts.
// 8-way row split (blockIdx.y): each thread sums 64 rows, atomicAdd into cs.
__global__ __launch_bounds__(256) void colsum_all(
    const float* __restrict__ sa_wq, const float* __restrict__ sa_wk,
    const float* __restrict__ sa_wv, const float* __restrict__ ca_wq,
    const float* __restrict__ ff_w1,
    float* __restrict__ csA, float* __restrict__ csQ, float* __restrict__ csF)
{
    const int t = blockIdx.x * 256 + threadIdx.x;
    const int l = t >> 12, u = t & 4095;
    const int r0 = blockIdx.y * 64;
    const float* base;
    int stride;
    float* out;
    if (u < 1536) {
        const int p = u >> 9, h = (u >> 6) & 7, d = u & 63;
        const float* w = (p == 0) ? sa_wq : (p == 1) ? sa_wk : sa_wv;
        base = w + (size_t)(l * 8 + h) * 512 * 64 + d;
        stride = 64;
        out = &csA[l * 1536 + u];
    } else if (u < 2048) {
        const int v = u - 1536, h = v >> 6, d = v & 63;
        base = ca_wq + (size_t)(l * 8 + h) * 512 * 64 + d;
        stride = 64;
        out = &csQ[l * 512 + v];
    } else {
        const int f = u - 2048;
        base = ff_w1 + (size_t)l * 512 * 2048 + f;
        stride = 2048;
        out = &csF[l * 2048 + f];
    }
    const float* p = base + (size_t)r0 * stride;
    float s0 = 0.f, s1 = 0.f, s2 = 0.f, s3 = 0.f;
#pragma unroll 4
    for (int c = 0; c < 64; c += 4) {
        s0 += p[0];
        s1 += p[(size_t)stride];
        s2 += p[(size_t)2 * stride];
        s3 += p[(size_t)3 * stride];
        p += (size_t)4 * stride;
    }
    atomicAdd(out, (s0 + s1) + (s2 + s3));
}

// ---------------------------------------------------------------------------
// GEMM out[M][N] = A[M][K] * BT[N][K]^T. m97 geometry: 4 waves (2x2),
// BM=128, BK=32 double-buffered, counted vmcnt, 4 blocks/CU.
// BN=128: per-wave 64x64 (MI4,NI4). BN=64: per-wave 64x32 (MI4,NI2).
// Per tile: vmcnt(VG)+bar; 8|6 ds_read_b128; lgkmcnt(0)+bar; stage t+2;
// 16|8 MFMA (compiler interleaves lgkm waits). Never vmcnt(0) in-loop.
// LN fixup (slotPrev>=0): val*rstd + bias - mu*rstd*cs[n].
// MODE 0: SA QKV (N=1536, fixup) -> qb/kb/vTb
// MODE 1: CA Q   (N=512, fixup)  -> qb
// MODE 2: CA KV  (N=1024, plain bias) -> kb/vTb
// MODE 3: FFN1   (fixup + relu) -> hbuf bf16
// MODE 4: FFN2   (plain bias + residual-normfix add into y, fused stats)
template <int MODE, int BN>
__global__ __launch_bounds__(256, 4) void gemm_bt(
    const bf16* __restrict__ A, const bf16* __restrict__ BT,
    const float* __restrict__ b0, const float* __restrict__ b1,
    const float* __restrict__ b2, const float* __restrict__ cs,
    float2* __restrict__ part, int slotPrev, int slotNew,
    bf16* __restrict__ o0, bf16* __restrict__ o1, bf16* __restrict__ o2,
    float* __restrict__ y, bf16* __restrict__ ybf, int N, int K)
{
    constexpr int MI = 4;
    constexpr int NI = BN / 32;          // 128 -> 4, 64 -> 2
    constexpr int BGLL = BN / 64;        // B GLLs per wave per K-tile
    constexpr int VG = 2 + BGLL;         // total GLLs per wave per K-tile
    __shared__ alignas(16) bf16 as[2][128][32];
    __shared__ alignas(16) bf16 bs[2][BN][32];
    const int tid = threadIdx.x, wave = tid >> 6, lane = tid & 63;

    // bijective XCD-aware swizzle of the flat (x-fastest) workgroup id
    const int gx = gridDim.x;
    int wgid = blockIdx.y * gx + blockIdx.x;
    {
        const int nwg = gx * gridDim.y;
        const int q = nwg >> 3, r = nwg & 7;
        const int xcd = wgid & 7, idx = wgid >> 3;
        wgid = (xcd < r ? xcd * (q + 1) : r * (q + 1) + (xcd - r) * q) + idx;
    }
    const int m0 = (wgid / gx) * 128, n0 = (wgid % gx) * BN;

    const int wr = (wave >> 1) * 64;
    const int wc = (wave & 1) * (BN / 2);
    const int fr = lane & 15, fq = lane >> 4;
    const int xr = fr & 3;

    float mu = 0.f, rstd = 1.f;
    if (slotPrev >= 0) {
        float2 p = part[slotPrev * 64 + (m0 >> 7)];
        mu = p.x * LNINV;
        rstd = rsqrtf(p.y * LNINV - mu * mu + EPS_);
    }

    // staging: one GLL16 covers 16 rows x 64B (4 lanes/row, 16B/lane).
    // LDS dest linear; GLOBAL source chunk pre-swizzled: physical chunk c of
    // row r holds logical chunk c ^ (r&3).
    const int rlane = lane >> 2;                    // row within 16-row group
    const int scol = ((lane & 3) ^ (rlane & 3)) * 8;  // swizzled col (elems)
    const bf16* pa = A + (size_t)(m0 + wave * 32 + rlane) * K + scol;
    const bf16* pb = BT + (size_t)(n0 + wave * (BGLL * 16) + rlane) * K + scol;

    auto stage = [&](int buf, int k0) {
#pragma unroll
        for (int i = 0; i < 2; ++i)
            GLL16(pa + k0 + (size_t)(16 * i) * K, &as[buf][wave * 32 + 16 * i][0]);
#pragma unroll
        for (int i = 0; i < BGLL; ++i)
            GLL16(pb + k0 + (size_t)(16 * i) * K, &bs[buf][wave * (BGLL * 16) + 16 * i][0]);
    };

    f32x4 acc[MI][NI] = {};
    bf16x8 af[MI], bfv[NI];
    auto frags = [&](int buf) {
#pragma unroll
        for (int mi = 0; mi < MI; ++mi)
            af[mi] = *(const bf16x8*)&as[buf][wr + mi * 16 + fr][(fq ^ xr) << 3];
#pragma unroll
        for (int ni = 0; ni < NI; ++ni)
            bfv[ni] = *(const bf16x8*)&bs[buf][wc + ni * 16 + fr][(fq ^ xr) << 3];
    };
    auto cluster = [&]() {
#pragma unroll
        for (int mi = 0; mi < MI; ++mi)
#pragma unroll
            for (int ni = 0; ni < NI; ++ni)
                acc[mi][ni] = MFMA16(af[mi], bfv[ni], acc[mi][ni]);
    };

    const int nt = K >> 5;           // K-tiles of 32
    stage(0, 0);
    stage(1, 32);

    int cur = 0;
    for (int t = 0; t < nt - 1; ++t) {
        // tile t's loads landed (tile t+1 stays in flight); make visible.
        asm volatile("s_waitcnt vmcnt(%0)\n\ts_barrier" :: "n"(VG) : "memory");
        frags(cur);
        // all waves done reading buf cur -> safe to refill it (2 ahead).
        asm volatile("s_waitcnt lgkmcnt(0)\n\ts_barrier" ::: "memory");
        if (t + 2 < nt) stage(cur, (t + 2) << 5);
        cluster();
        cur ^= 1;
    }
    asm volatile("s_waitcnt vmcnt(0)\n\ts_barrier" ::: "memory");
    frags(cur);
    cluster();

    float s = 0.f, ss = 0.f;
    const float murs = mu * rstd;
#pragma unroll
    for (int mi = 0; mi < MI; ++mi) {
#pragma unroll
        for (int ni = 0; ni < NI; ++ni) {
            const int n = n0 + wc + ni * 16 + fr;
#pragma unroll
            for (int reg = 0; reg < 4; ++reg) {
                const int r = m0 + wr + mi * 16 + fq * 4 + reg;
                float val = acc[mi][ni][reg];
                if constexpr (MODE == 0) {
                    const int p = n >> 9, hd = n & 511, d = n & 63, hh = (n >> 6) & 7;
                    const int bb = r >> 7, tt = r & 127;
                    const float* bias = (p == 0) ? b0 : (p == 1 ? b1 : b2);
                    val = val * rstd + bias[hd] - murs * cs[n];
                    const size_t bh = (size_t)(bb * 8 + hh);
                    if (p == 0)      o0[(bh * 128 + tt) * 64 + d] = (bf16)val;
                    else if (p == 1) o1[(bh * 128 + tt) * 64 + d] = (bf16)val;
                    else             o2[(bh * 64 + d) * 128 + tt] = (bf16)val;
                } else if constexpr (MODE == 1) {
                    const int d = n & 63, hh = (n >> 6) & 7;
                    const int bb = r >> 7, tt = r & 127;
                    val = val * rstd + b0[n] - murs * cs[n];
                    o0[((size_t)(bb * 8 + hh) * 128 + tt) * 64 + d] = (bf16)val;
                } else if constexpr (MODE == 2) {
                    const int p = n >> 9, hd = n & 511, d = n & 63, hh = (n >> 6) & 7;
                    const int bb = r >> 7, tt = r & 127;
                    val += (p == 0) ? b1[hd] : b2[hd];
                    const size_t bh = (size_t)(bb * 8 + hh);
                    if (p == 0) o1[(bh * 128 + tt) * 64 + d] = (bf16)val;
                    else        o2[(bh * 64 + d) * 128 + tt] = (bf16)val;
                } else if constexpr (MODE == 3) {
                    val = val * rstd + b0[n] - murs * cs[n];
                    val = fmaxf(val, 0.f);
                    o0[(size_t)r * 2048 + n] = (bf16)val;
                } else {  // MODE 4: residual-normfix add + fused stats
                    const size_t idx = (size_t)r * 512 + n;
                    const float v = (y[idx] - mu) * rstd + val + b0[n];
                    y[idx] = v;
                    ybf[idx] = (bf16)v;
                    s += v;
                    ss += v * v;
                }
            }
        }
    }
    if constexpr (MODE == 4) {
        for (int off = 32; off; off >>= 1) { s += __shfl_xor(s, off); ss += __shfl_xor(ss, off); }
        __shared__ float rs[4], rss[4];
        if (lane == 0) { rs[wave] = s; rss[wave] = ss; }
        __syncthreads();
        if (tid == 0) {
            float2* dst = &part[slotNew * 64 + (m0 >> 7)];
            atomicAdd(&dst->x, rs[0] + rs[1] + rs[2] + rs[3]);
            atomicAdd(&dst->y, rss[0] + rss[1] + rss[2] + rss[3]);
        }
    }
}

// ---------------------------------------------------------------------------
// Attention for one (b,h). exp fused into QK epilogue (in-register), row-sums
// via shfl reduce + 2-way LDS partials (no max: |S|~O(1), shift-invariant).
// Epilogue: y += normfix(residual) + P V / rowsum, fused stats -> part.
__global__ __launch_bounds__(256) void attn_kernel(
    const bf16* __restrict__ q, const bf16* __restrict__ k,
    const bf16* __restrict__ vT, float* __restrict__ y, bf16* __restrict__ ybf,
    float2* __restrict__ part, int slotPrev, int slotNew)
{
    __shared__ alignas(16) bf16 sP[128][136];
    __shared__ float sPart[2][128];
    const int bh = blockIdx.x;
    const int bb = bh >> 3, hh = bh & 7;
    const bf16* Q = q + (size_t)bh * 128 * 64;
    const bf16* Kp = k + (size_t)bh * 128 * 64;
    const bf16* V = vT + (size_t)bh * 64 * 128;
    const int tid = threadIdx.x, wave = tid >> 6, lane = tid & 63;
    const int wr = (wave >> 1) * 64, wc = (wave & 1) * 64;
    const int fr = lane & 15, fq = lane >> 4;

    float mu = 0.f, rstd = 1.f;
    if (slotPrev >= 0) {
        float2 p = part[slotPrev * 64 + bb];
        mu = p.x * LNINV;
        rstd = rsqrtf(p.y * LNINV - mu * mu + EPS_);
    }

    // S = Q K^T (128x128, K=64)
    f32x4 acc[4][4] = {};
#pragma unroll
    for (int k0 = 0; k0 < 64; k0 += 32) {
        bf16x8 af[4], bfv[4];
#pragma unroll
        for (int mi = 0; mi < 4; ++mi)
            af[mi] = *(const bf16x8*)(Q + (size_t)(wr + mi * 16 + fr) * 64 + k0 + fq * 8);
#pragma unroll
        for (int ni = 0; ni < 4; ++ni)
            bfv[ni] = *(const bf16x8*)(Kp + (size_t)(wc + ni * 16 + fr) * 64 + k0 + fq * 8);
#pragma unroll
        for (int mi = 0; mi < 4; ++mi)
#pragma unroll
            for (int ni = 0; ni < 4; ++ni)
                acc[mi][ni] = MFMA16(af[mi], bfv[ni], acc[mi][ni]);
    }

    // P = exp(S/8) in registers; store P + per-(wavecol,row) partial sums
    const int colw = wave & 1;
#pragma unroll
    for (int mi = 0; mi < 4; ++mi) {
#pragma unroll
        for (int reg = 0; reg < 4; ++reg) {
            const int r = wr + mi * 16 + fq * 4 + reg;
            float rsum = 0.f;
#pragma unroll
            for (int ni = 0; ni < 4; ++ni) {
                const float e = __expf(acc[mi][ni][reg] * 0.125f);
                sP[r][wc + ni * 16 + fr] = (bf16)e;
                rsum += e;
            }
            rsum += __shfl_xor(rsum, 1);
            rsum += __shfl_xor(rsum, 2);
            rsum += __shfl_xor(rsum, 4);
            rsum += __shfl_xor(rsum, 8);
            if (fr == 0) sPart[colw][r] = rsum;
        }
    }
    __syncthreads();

    // O = P V (128x64, K=128)
    f32x4 acc2[2][4] = {};
#pragma unroll
    for (int k0 = 0; k0 < 128; k0 += 32) {
        bf16x8 af[2], bfv[4];
#pragma unroll
        for (int mi = 0; mi < 2; ++mi)
            af[mi] = *(const bf16x8*)&sP[wave * 32 + mi * 16 + fr][k0 + fq * 8];
#pragma unroll
        for (int ni = 0; ni < 4; ++ni)
            bfv[ni] = *(const bf16x8*)(V + (size_t)(ni * 16 + fr) * 128 + k0 + fq * 8);
#pragma unroll
        for (int mi = 0; mi < 2; ++mi)
#pragma unroll
            for (int ni = 0; ni < 4; ++ni)
                acc2[mi][ni] = MFMA16(af[mi], bfv[ni], acc2[mi][ni]);
    }

    float inv[2][4];
#pragma unroll
    for (int mi = 0; mi < 2; ++mi)
#pragma unroll
        for (int reg = 0; reg < 4; ++reg) {
            const int r = wave * 32 + mi * 16 + fq * 4 + reg;
            inv[mi][reg] = 1.f / (sPart[0][r] + sPart[1][r]);
        }

    float s = 0.f, ss = 0.f;
#pragma unroll
    for (int mi = 0; mi < 2; ++mi)
#pragma unroll
        for (int ni = 0; ni < 4; ++ni)
#pragma unroll
            for (int reg = 0; reg < 4; ++reg) {
                const int r = wave * 32 + mi * 16 + fq * 4 + reg;
                const int d = ni * 16 + fr;
                const size_t idx = ((size_t)(bb * 128 + r)) * 512 + hh * 64 + d;
                const float v = (y[idx] - mu) * rstd + acc2[mi][ni][reg] * inv[mi][reg];
                y[idx] = v;
                ybf[idx] = (bf16)v;
                s += v;
                ss += v * v;
            }
    for (int off = 32; off; off >>= 1) { s += __shfl_xor(s, off); ss += __shfl_xor(ss, off); }
    __shared__ float rs[4], rss[4];
    if (lane == 0) { rs[wave] = s; rss[wave] = ss; }
    __syncthreads();
    if (tid == 0) {
        float2* dst = &part[slotNew * 64 + bb];
        atomicAdd(&dst->x, rs[0] + rs[1] + rs[2] + rs[3]);
        atomicAdd(&dst->y, rss[0] + rss[1] + rss[2] + rss[3]);
    }
}

// ---------------------------------------------------------------------------
// d_out = (y - mu) * rstd, fp32. grid 4096 x 256, 4 elems/thread.
__global__ __launch_bounds__(256) void final_norm(
    const float* __restrict__ y, const float2* __restrict__ part, int slot,
    float* __restrict__ out)
{
    const size_t i = ((size_t)blockIdx.x * 256 + threadIdx.x) * 4;
    const int b = (int)(i >> 16);
    float2 p = part[slot * 64 + b];
    const float mu = p.x * LNINV;
    const float rstd = rsqrtf(p.y * LNINV - mu * mu + EPS_);
    float4 v = *(const float4*)(y + i);
    float4 o = {(v.x - mu) * rstd, (v.y - mu) * rstd, (v.z - mu) * rstd, (v.w - mu) * rstd};
    *(float4*)(out + i) = o;
}

// ---------------------------------------------------------------------------
extern "C" void kernel_launch(void* const* d_in, const int* in_sizes, int n_in,
                              void* d_out, int out_size, void* d_ws, size_t ws_size,
                              hipStream_t stream)
{
    (void)in_sizes; (void)n_in; (void)out_size; (void)ws_size;
    const float* x_in  = (const float*)d_in[0];
    const float* enc   = (const float*)d_in[1];
    const float* sa_wq = (const float*)d_in[2];
    const float* sa_bq = (const float*)d_in[3];
    const float* sa_wk = (const float*)d_in[4];
    const float* sa_bk = (const float*)d_in[5];
    const float* sa_wv = (const float*)d_in[6];
    const float* sa_bv = (const float*)d_in[7];
    const float* ca_wq = (const float*)d_in[8];
    const float* ca_bq = (const float*)d_in[9];
    const float* ca_wk = (const float*)d_in[10];
    const float* ca_bk = (const float*)d_in[11];
    const float* ca_wv = (const float*)d_in[12];
    const float* ca_bv = (const float*)d_in[13];
    const float* ff_w1 = (const float*)d_in[14];
    const float* ff_b1 = (const float*)d_in[15];
    const float* ff_w2 = (const float*)d_in[16];
    const float* ff_b2 = (const float*)d_in[17];

    char* wsp = (char*)d_ws;
    auto alloc = [&](size_t bytes) -> char* {
        char* p = wsp;
        wsp += (bytes + 255) & ~(size_t)255;
        return p;
    };
    float* y     = (float*)alloc((size_t)M_ * 512 * 4);           // unnormalized stream
    bf16*  ybf   = (bf16*)alloc((size_t)M_ * 512 * 2);            // bf16 GEMM operand
    bf16*  encbf = (bf16*)alloc((size_t)M_ * 512 * 2);
    char*  shreg = alloc((size_t)M_ * 2048 * 2);                  // qkv bufs / FFN hidden
    bf16*  WsaA  = (bf16*)alloc((size_t)L_ * 1536 * 512 * 2);     // repacked, all layers
    bf16*  WcaqA = (bf16*)alloc((size_t)L_ * 512 * 512 * 2);
    bf16*  WcakvA= (bf16*)alloc((size_t)L_ * 1024 * 512 * 2);
    bf16*  Wff1A = (bf16*)alloc((size_t)L_ * 2048 * 512 * 2);     // all layers
    bf16*  Wff2A = (bf16*)alloc((size_t)L_ * 512 * 2048 * 2);
    float* csA   = (float*)alloc((size_t)L_ * 1536 * 4);          // colsums
    float* csQ   = (float*)alloc((size_t)L_ * 512 * 4);
    float* csF   = (float*)alloc((size_t)L_ * 2048 * 4);
    float2* part = (float2*)alloc(18 * 64 * sizeof(float2));

    bf16* qb   = (bf16*)shreg;
    bf16* kb   = (bf16*)(shreg + (size_t)512 * 128 * 64 * 2);
    bf16* vTb  = (bf16*)(shreg + (size_t)2 * 512 * 128 * 64 * 2);
    bf16* hbuf = (bf16*)shreg;  // overlaps qkv (disjoint lifetime)

    dim3 tb(256);
    zero_all<<<48, tb, 0, stream>>>(csA, csQ, csF, (float*)part);
    init_x<<<2048, tb, 0, stream>>>(x_in, y, ybf);
    to_bf16<<<2048, tb, 0, stream>>>(enc, encbf);
    head_repack<<<dim3(1, 8, 288), tb, 0, stream>>>(sa_wq, sa_wk, sa_wv, ca_wq, ca_wk, ca_wv,
                                                    WsaA, WcaqA, WcakvA);
    ff_repack<<<dim3(32, 8, 12), tb, 0, stream>>>(ff_w1, ff_w2, Wff1A, Wff2A);
    colsum_all<<<dim3(96, 8), tb, 0, stream>>>(sa_wq, sa_wk, sa_wv, ca_wq, ff_w1, csA, csQ, csF);

    for (int l = 0; l < L_; ++l) {
        const int sPrev = (l == 0) ? -1 : (l - 1) * 3 + 2;
        // ---- self attention
        gemm_bt<0, 128><<<dim3(12, 64), tb, 0, stream>>>(ybf, WsaA + (size_t)l * 1536 * 512,
            sa_bq + l * 512, sa_bk + l * 512, sa_bv + l * 512, csA + l * 1536,
            part, sPrev, -1, qb, kb, vTb, nullptr, nullptr, 1536, 512);
        attn_kernel<<<512, tb, 0, stream>>>(qb, kb, vTb, y, ybf, part, sPrev, l * 3 + 0);
        // ---- cross attention
        gemm_bt<1, 64><<<dim3(8, 64), tb, 0, stream>>>(ybf, WcaqA + (size_t)l * 512 * 512,
            ca_bq + l * 512, nullptr, nullptr, csQ + l * 512,
            part, l * 3 + 0, -1, qb, nullptr, nullptr, nullptr, nullptr, 512, 512);
        gemm_bt<2, 128><<<dim3(8, 64), tb, 0, stream>>>(encbf, WcakvA + (size_t)l * 1024 * 512,
            nullptr, ca_bk + l * 512, ca_bv + l * 512, nullptr,
            part, -1, -1, nullptr, kb, vTb, nullptr, nullptr, 1024, 512);
        attn_kernel<<<512, tb, 0, stream>>>(qb, kb, vTb, y, ybf, part, l * 3 + 0, l * 3 + 1);
        // ---- feed-forward
        gemm_bt<3, 128><<<dim3(16, 64), tb, 0, stream>>>(ybf, Wff1A + (size_t)l * 2048 * 512,
            ff_b1 + l * 2048, nullptr, nullptr, csF + l * 2048,
            part, l * 3 + 1, -1, hbuf, nullptr, nullptr, nullptr, nullptr, 2048, 512);
        gemm_bt<4, 64><<<dim3(8, 64), tb, 0, stream>>>(hbuf, Wff2A + (size_t)l * 512 * 2048,
            ff_b2 + l * 512, nullptr, nullptr, nullptr,
            part, l * 3 + 1, l * 3 + 2, nullptr, nullptr, nullptr, y, ybf, 512, 2048);
    }
    final_norm<<<4096, tb, 0, stream>>>(y, part, 17, (float*)d_out);
}